// Round 10
// baseline (187.254 us; speedup 1.0000x reference)
//
#include <hip/hip_runtime.h>

// ---------------------------------------------------------------------------
// GMMConv forward — int8-gather, staged-scale edition:
//  0) convert_W: Wp[j'][k]=f16(W_fc[((j'&3)<<6)|(j'>>2)][k]) into a 128 KB
//     overlay at the start of d_out (edge rewrites all of d_out afterwards).
//  1) gemm_fused (FROZEN from R9): f16 MFMA, A staged fp32->f16 once per
//     block, B-tiles DMA'd from L2-resident Wp; epilogue quantizes to i8
//     with per-(row, 64-col-group) scales via shfl_xor absmax reduce,
//     coalesced stores through LDS.
//  2) edge_aggregate: one wave per dst node (CSR rowptr sorts edges by dst,
//     no atomics). NEW: per 16-edge chunk, after cw is published, all 64
//     lanes gather the chunk's 64 scale dwords into LDS in ONE parallel
//     instruction (latency overlapped by pseudo+exp staging). Inner loop is
//     then exactly 1 VMEM / 2 cache lines per edge (nfq dword) + sdot4 +
//     LDS-broadcast scale -> line floor 2/edge (was 3/edge in R9, which
//     measured at the ~5-6 TB/s fabric wall).
// ---------------------------------------------------------------------------

typedef _Float16 f16;
typedef __attribute__((ext_vector_type(4))) _Float16 f16x4;
typedef __attribute__((ext_vector_type(8))) _Float16 f16x8;
typedef __attribute__((ext_vector_type(4))) float f32x4;

__device__ inline f16x4 cvt4h(float4 v) {
    f16x4 h;
    h.x = (f16)v.x; h.y = (f16)v.y; h.z = (f16)v.z; h.w = (f16)v.w;
    return h;
}

__device__ inline int dot4_i8(int a, int b) {
#if __has_builtin(__builtin_amdgcn_sdot4)
    return __builtin_amdgcn_sdot4(a, b, 0, false);
#else
    return (int)(char)(a)       * (int)(char)(b)
         + (int)(char)(a >> 8)  * (int)(char)(b >> 8)
         + (int)(char)(a >> 16) * (int)(char)(b >> 16)
         + (int)(char)(a >> 24) * (int)(char)(b >> 24);
#endif
}

// W_fc fp32 [256][256] -> Wp f16 [256][256] with permuted rows.
__global__ __launch_bounds__(256) void convert_W(
    const float* __restrict__ W, f16* __restrict__ Wp)
{
    const int gid = blockIdx.x * 256 + threadIdx.x;   // 64 blocks -> 16384
    const int jp = gid >> 6, k4 = gid & 63;
    const int wrow = ((jp & 3) << 6) | (jp >> 2);
    reinterpret_cast<f16x4*>(Wp)[jp * 64 + k4] =
        cvt4h(reinterpret_cast<const float4*>(W)[wrow * 64 + k4]);
}

#define ASTRIDE 264                 // f16 per A-row in LDS (+8 pad)
#define AS_BYTES (64 * ASTRIDE * 2) // 33792, 16B aligned

// nfq[m][jp] = i8 quant of sum_k f16(feat[m][k]) * Wp[jp][k]
// sc[m][g]   = groupAbsmax / 127^2 for col group g = jp>>6
__global__ __launch_bounds__(256) void gemm_fused(
    const float* __restrict__ feat,   // fp32 [M][256]
    const f16* __restrict__ Wp,       // f16 [256][256] permuted rows
    char* __restrict__ nfq,           // i8 [M][256]
    float* __restrict__ sc,           // f32 [M][4]
    int M)
{
    __shared__ char smem[AS_BYTES + 256 * 32 * 2];  // As 33 KB + Bs/qt 16 KB
    f16* As = (f16*)smem;
    f16* Bs = (f16*)(smem + AS_BYTES);
    char* qt = smem + AS_BYTES;       // reuses Bs region in the epilogue
    const int t    = threadIdx.x;
    const int lane = t & 63;
    const int wave = t >> 6;
    const int bm   = blockIdx.x * 64;
    const int l16  = lane & 15;
    const int quad = lane >> 4;
    const int wn   = wave * 64;

    size_t bsrc[4];
#pragma unroll
    for (int j = 0; j < 4; ++j)
        bsrc[j] = (size_t)(wave * 64 + j * 16 + (lane >> 2)) * 256 + (lane & 3) * 8;

    typedef __attribute__((address_space(3))) void lds_t;
    typedef const __attribute__((address_space(1))) void gm_t;

    // kick off B DMA for k0=0, then stage A (fp32->f16) while it flies
#pragma unroll
    for (int j = 0; j < 4; ++j)
        __builtin_amdgcn_global_load_lds((gm_t*)(Wp + bsrc[j]),
            (lds_t*)(Bs + (wave * 4 + j) * 512), 16, 0, 0);

#pragma unroll
    for (int it = 0; it < 8; ++it) {
        const int flat = it * 2048 + t * 8;
        const int row  = flat >> 8;              // 0..63
        const int koff = flat & 255;
        const float* src = feat + (size_t)min(bm + row, M - 1) * 256 + koff;
        const float4 a0 = *reinterpret_cast<const float4*>(src);
        const float4 a1 = *reinterpret_cast<const float4*>(src + 4);
        *reinterpret_cast<f16x4*>(&As[row * ASTRIDE + koff])     = cvt4h(a0);
        *reinterpret_cast<f16x4*>(&As[row * ASTRIDE + koff + 4]) = cvt4h(a1);
    }

    f32x4 acc[4][4];
#pragma unroll
    for (int mi = 0; mi < 4; ++mi)
#pragma unroll
        for (int ni = 0; ni < 4; ++ni)
            acc[mi][ni] = (f32x4){0.f, 0.f, 0.f, 0.f};

    for (int ki = 0; ki < 8; ++ki) {
        __syncthreads();                         // Bs(ki) + As ready

        f16x8 af[4], bfr[4];
#pragma unroll
        for (int mi = 0; mi < 4; ++mi)
            af[mi] = *reinterpret_cast<const f16x8*>(
                &As[(mi * 16 + l16) * ASTRIDE + ki * 32 + quad * 8]);
#pragma unroll
        for (int ni = 0; ni < 4; ++ni)
            bfr[ni] = *reinterpret_cast<const f16x8*>(
                &Bs[(wn + ni * 16 + l16) * 32 + quad * 8]);

        __syncthreads();                         // all waves done reading Bs
        if (ki < 7) {
            const int k0 = (ki + 1) * 32;
#pragma unroll
            for (int j = 0; j < 4; ++j)
                __builtin_amdgcn_global_load_lds((gm_t*)(Wp + bsrc[j] + k0),
                    (lds_t*)(Bs + (wave * 4 + j) * 512), 16, 0, 0);
        }
#pragma unroll
        for (int mi = 0; mi < 4; ++mi)
#pragma unroll
            for (int ni = 0; ni < 4; ++ni)
                acc[mi][ni] = __builtin_amdgcn_mfma_f32_16x16x32_f16(
                    af[mi], bfr[ni], acc[mi][ni], 0, 0, 0);
    }
    // After the ki=7 second barrier: no more Bs reads -> qt may reuse Bs.

    // quantize: per (row, this wave's 64 cols) absmax
    // C/D layout: col = lane&15, row = quad*4 + reg  [m89; dtype-independent]
#pragma unroll
    for (int mi = 0; mi < 4; ++mi) {
#pragma unroll
        for (int r = 0; r < 4; ++r) {
            float am = 0.f;
#pragma unroll
            for (int ni = 0; ni < 4; ++ni)
                am = fmaxf(am, fabsf(acc[mi][ni][r]));
            am = fmaxf(am, __shfl_xor(am, 1));   // reduce over l16 (same quad)
            am = fmaxf(am, __shfl_xor(am, 2));
            am = fmaxf(am, __shfl_xor(am, 4));
            am = fmaxf(am, __shfl_xor(am, 8));
            const float sinv = am > 0.f ? 127.f / am : 0.f;
            const int rl = mi * 16 + quad * 4 + r;
#pragma unroll
            for (int ni = 0; ni < 4; ++ni)
                qt[rl * 256 + wn + ni * 16 + l16] =
                    (char)(int)__builtin_rintf(acc[mi][ni][r] * sinv);
            if (l16 == 0) {
                const int row = bm + rl;
                if (row < M) sc[row * 4 + wave] = am * (1.f / 16129.f);
            }
        }
    }
    __syncthreads();

    // coalesced i8 store: thread t -> row t>>2, 64 B chunk (t&3)
    {
        const int rl  = t >> 2;
        const int co  = (t & 3) * 64;
        const int row = bm + rl;
        if (row < M) {
            const int4* s4 = reinterpret_cast<const int4*>(qt + rl * 256 + co);
            int4* d4 = reinterpret_cast<int4*>(nfq + (size_t)row * 256 + co);
#pragma unroll
            for (int j = 0; j < 4; ++j) d4[j] = s4[j];
        }
    }
}

// One wave per destination node; lane = feature f (F=64). 2 waves/block.
__global__ __launch_bounds__(128) void edge_aggregate(
    const int* __restrict__ rowptr,
    const int* __restrict__ colind,
    const float* __restrict__ pseudo,   // [E][2]
    const char* __restrict__ nfq,       // i8 [N][256] permuted [f*4+k]
    const float* __restrict__ sc,       // f32 [N][4] group scales
    const float* __restrict__ mu,
    const float* __restrict__ inv_sigma,
    const float* __restrict__ bias,
    float* __restrict__ out,            // [N][64]
    int N)
{
    __shared__ int   gpack[2][16];      // per-wave: 16 edges, g quantized i8x4
    __shared__ int   cbuf[2][16];
    __shared__ float sbuf[2][64];       // per-wave: 16 edges x 4 group scales
    const int wave = threadIdx.x >> 6;
    const int lane = threadIdx.x & 63;
    const int node = blockIdx.x * 2 + wave;
    if (node >= N) return;          // wave-uniform exit; no block barriers below

    const int kk = lane >> 4;
    const int ii = lane & 15;
    const float mx = mu[2 * kk], my = mu[2 * kk + 1];
    const float sa = inv_sigma[2 * kk], sb = inv_sigma[2 * kk + 1];
    const float sx = sa * sa, sy = sb * sb;

    const int e0 = rowptr[node];
    const int e1 = rowptr[node + 1];
    int*   gp = gpack[wave];
    int*   cw = cbuf[wave];
    float* sw = sbuf[wave];

    float a4[4] = {0.f, 0.f, 0.f, 0.f};   // 4 independent chains
    for (int ec = e0; ec < e1; ec += 16) {
        const int cnt = min(16, e1 - ec);
        // phase 1: publish colinds; start gaussian math
        const bool v = ii < cnt;
        const int e = v ? (ec + ii) : e0;
        if (kk == 0) cw[ii] = v ? colind[e] : 0;
        const float2 p = *reinterpret_cast<const float2*>(pseudo + 2 * (size_t)e);
        __builtin_amdgcn_wave_barrier();
        __threadfence_block();      // cw visible
        // phase 2: 64-lane parallel scale gather (one instruction for the
        // whole chunk) overlapped with exp; publish g bytes
        const int cl = cw[ii];
        const float s_l = sc[cl * 4 + kk];
        const float dx = p.x - mx, dy = p.y - my;
        const float g = v ? __expf(-0.5f * (dx * dx * sx + dy * dy * sy)) : 0.f;
        ((char*)&gp[ii])[kk] = (char)(int)(g * 127.f + 0.5f);  // 0..127
        sw[ii * 4 + kk] = s_l;
        __builtin_amdgcn_wave_barrier();
        __threadfence_block();      // gp + sw visible
        // inner loop: exactly 1 VMEM (nfq dword) per edge
        const int cnt4 = (cnt + 3) & ~3;
        for (int i2 = 0; i2 < cnt4; i2 += 4) {
#pragma unroll
            for (int j = 0; j < 4; ++j) {
                const int c = cw[i2 + j];
                const int q = *reinterpret_cast<const int*>(
                    nfq + ((size_t)c << 8) + (lane << 2));
                const int d = dot4_i8(q, gp[i2 + j]);
                a4[j] += sw[(i2 + j) * 4 + kk] * (float)d;
            }
        }
        __builtin_amdgcn_wave_barrier();
        __threadfence_block();      // reads done before next chunk's writes
    }
    out[((size_t)node << 6) + lane] =
        (a4[0] + a4[1]) + (a4[2] + a4[3]) + bias[lane];
}

extern "C" void kernel_launch(void* const* d_in, const int* in_sizes, int n_in,
                              void* d_out, int out_size, void* d_ws, size_t ws_size,
                              hipStream_t stream)
{
    const int*   rowptr    = (const int*)d_in[0];
    const int*   colind    = (const int*)d_in[1];
    // d_in[2] colptr, d_in[3] rowind, d_in[4] permute: inert in forward math
    const float* feat      = (const float*)d_in[5];
    const float* pseudo    = (const float*)d_in[6];
    const float* W_fc      = (const float*)d_in[7];
    const float* mu        = (const float*)d_in[8];
    const float* inv_sigma = (const float*)d_in[9];
    const float* bias      = (const float*)d_in[10];
    float* out = (float*)d_out;

    const int N = in_sizes[0] - 1;        // 50000
    char*  nfq = (char*)d_ws;             // i8 [N][256] = 12.8 MB
    float* sc  = (float*)(nfq + (size_t)N * 256);  // f32 [N][4] = 0.8 MB
    f16*   Wp  = (f16*)d_out;             // 128 KB overlay; edge rewrites
                                          // all of d_out afterwards

    hipLaunchKernelGGL(convert_W, dim3(64), dim3(256), 0, stream, W_fc, Wp);

    hipLaunchKernelGGL(gemm_fused, dim3((N + 63) / 64), dim3(256), 0, stream,
                       feat, Wp, nfq, sc, N);

    hipLaunchKernelGGL(edge_aggregate, dim3((N + 1) / 2), dim3(128), 0, stream,
                       rowptr, colind, pseudo, nfq, sc, mu, inv_sigma, bias, out, N);
}

// Round 11
// 186.324 us; speedup vs baseline: 1.0050x; 1.0050x over previous
//
#include <hip/hip_runtime.h>

// ---------------------------------------------------------------------------
// GMMConv forward — int8-gather, barrier-free-edge edition:
//  0) prep: (a) Wp[j'][k]=f16(W_fc[((j'&3)<<6)|(j'>>2)][k]) into a 128 KB
//     overlay at the start of d_out (edge rewrites d_out afterwards);
//     (b) gq[e] = i8x4 pack of the 4 per-edge gaussians (exp moved OUT of
//     the hot gather kernel; streaming, coalesced).
//  1) gemm_fused (FROZEN from R9): f16 MFMA, A staged fp32->f16 once per
//     block, B-tiles DMA'd from L2-resident Wp; epilogue quantizes to i8
//     with per-(row, 64-col-group) scales (shfl_xor absmax reduce).
//  2) edge_aggregate: one wave per dst node (CSR rowptr sorts edges by dst,
//     no atomics). NO LDS, NO barriers: chunk metadata (colind, gq, sc) is
//     loaded by 16 lanes in parallel and broadcast via shuffles; all 16 nfq
//     gathers of a chunk are issued back-to-back (16-deep MLP), then 16
//     sdot4+fma on 4 independent accumulator chains.
//     Rationale: R8->R10 showed time is insensitive to lines/edge (4->2) at
//     ~58 us; FETCH pinned at 96 MB = 8 XCD x nfq (compulsory). The residual
//     is serial chunk structure (3 dependent latencies + 2 barriers + exp),
//     which this version eliminates.
// ---------------------------------------------------------------------------

typedef _Float16 f16;
typedef __attribute__((ext_vector_type(4))) _Float16 f16x4;
typedef __attribute__((ext_vector_type(8))) _Float16 f16x8;
typedef __attribute__((ext_vector_type(4))) float f32x4;

__device__ inline f16x4 cvt4h(float4 v) {
    f16x4 h;
    h.x = (f16)v.x; h.y = (f16)v.y; h.z = (f16)v.z; h.w = (f16)v.w;
    return h;
}

__device__ inline int dot4_i8(int a, int b) {
#if __has_builtin(__builtin_amdgcn_sdot4)
    return __builtin_amdgcn_sdot4(a, b, 0, false);
#else
    return (int)(char)(a)       * (int)(char)(b)
         + (int)(char)(a >> 8)  * (int)(char)(b >> 8)
         + (int)(char)(a >> 16) * (int)(char)(b >> 16)
         + (int)(char)(a >> 24) * (int)(char)(b >> 24);
#endif
}

// (a) W_fc fp32 -> Wp f16 permuted rows; (b) gq[e] = i8x4 gaussians.
__global__ __launch_bounds__(256) void prep(
    const float* __restrict__ W, const float* __restrict__ pseudo,
    const float* __restrict__ mu, const float* __restrict__ inv_sigma,
    f16* __restrict__ Wp, int* __restrict__ gq, int E)
{
    const int gid = blockIdx.x * 256 + threadIdx.x;
    if (gid < 16384) {
        const int jp = gid >> 6, k4 = gid & 63;
        const int wrow = ((jp & 3) << 6) | (jp >> 2);
        reinterpret_cast<f16x4*>(Wp)[jp * 64 + k4] =
            cvt4h(reinterpret_cast<const float4*>(W)[wrow * 64 + k4]);
    }
    float mx[4], my[4], sx[4], sy[4];
#pragma unroll
    for (int k = 0; k < 4; ++k) {
        mx[k] = mu[2 * k];
        my[k] = mu[2 * k + 1];
        const float a = inv_sigma[2 * k], b = inv_sigma[2 * k + 1];
        sx[k] = a * a; sy[k] = b * b;
    }
    for (int e = gid; e < E; e += gridDim.x * 256) {
        const float2 p = reinterpret_cast<const float2*>(pseudo)[e];
        int pack = 0;
#pragma unroll
        for (int k = 0; k < 4; ++k) {
            const float dx = p.x - mx[k], dy = p.y - my[k];
            const float g = __expf(-0.5f * (dx * dx * sx[k] + dy * dy * sy[k]));
            pack |= ((int)(g * 127.f + 0.5f) & 0xff) << (8 * k);
        }
        gq[e] = pack;
    }
}

#define ASTRIDE 264                 // f16 per A-row in LDS (+8 pad)
#define AS_BYTES (64 * ASTRIDE * 2) // 33792, 16B aligned

// nfq[m][jp] = i8 quant of sum_k f16(feat[m][k]) * Wp[jp][k]
// sc[m][g]   = groupAbsmax / 127^2 for col group g = jp>>6
__global__ __launch_bounds__(256) void gemm_fused(
    const float* __restrict__ feat,   // fp32 [M][256]
    const f16* __restrict__ Wp,       // f16 [256][256] permuted rows
    char* __restrict__ nfq,           // i8 [M][256]
    float* __restrict__ sc,           // f32 [M][4]
    int M)
{
    __shared__ char smem[AS_BYTES + 256 * 32 * 2];  // As 33 KB + Bs/qt 16 KB
    f16* As = (f16*)smem;
    f16* Bs = (f16*)(smem + AS_BYTES);
    char* qt = smem + AS_BYTES;       // reuses Bs region in the epilogue
    const int t    = threadIdx.x;
    const int lane = t & 63;
    const int wave = t >> 6;
    const int bm   = blockIdx.x * 64;
    const int l16  = lane & 15;
    const int quad = lane >> 4;
    const int wn   = wave * 64;

    size_t bsrc[4];
#pragma unroll
    for (int j = 0; j < 4; ++j)
        bsrc[j] = (size_t)(wave * 64 + j * 16 + (lane >> 2)) * 256 + (lane & 3) * 8;

    typedef __attribute__((address_space(3))) void lds_t;
    typedef const __attribute__((address_space(1))) void gm_t;

    // kick off B DMA for k0=0, then stage A (fp32->f16) while it flies
#pragma unroll
    for (int j = 0; j < 4; ++j)
        __builtin_amdgcn_global_load_lds((gm_t*)(Wp + bsrc[j]),
            (lds_t*)(Bs + (wave * 4 + j) * 512), 16, 0, 0);

#pragma unroll
    for (int it = 0; it < 8; ++it) {
        const int flat = it * 2048 + t * 8;
        const int row  = flat >> 8;              // 0..63
        const int koff = flat & 255;
        const float* src = feat + (size_t)min(bm + row, M - 1) * 256 + koff;
        const float4 a0 = *reinterpret_cast<const float4*>(src);
        const float4 a1 = *reinterpret_cast<const float4*>(src + 4);
        *reinterpret_cast<f16x4*>(&As[row * ASTRIDE + koff])     = cvt4h(a0);
        *reinterpret_cast<f16x4*>(&As[row * ASTRIDE + koff + 4]) = cvt4h(a1);
    }

    f32x4 acc[4][4];
#pragma unroll
    for (int mi = 0; mi < 4; ++mi)
#pragma unroll
        for (int ni = 0; ni < 4; ++ni)
            acc[mi][ni] = (f32x4){0.f, 0.f, 0.f, 0.f};

    for (int ki = 0; ki < 8; ++ki) {
        __syncthreads();                         // Bs(ki) + As ready

        f16x8 af[4], bfr[4];
#pragma unroll
        for (int mi = 0; mi < 4; ++mi)
            af[mi] = *reinterpret_cast<const f16x8*>(
                &As[(mi * 16 + l16) * ASTRIDE + ki * 32 + quad * 8]);
#pragma unroll
        for (int ni = 0; ni < 4; ++ni)
            bfr[ni] = *reinterpret_cast<const f16x8*>(
                &Bs[(wn + ni * 16 + l16) * 32 + quad * 8]);

        __syncthreads();                         // all waves done reading Bs
        if (ki < 7) {
            const int k0 = (ki + 1) * 32;
#pragma unroll
            for (int j = 0; j < 4; ++j)
                __builtin_amdgcn_global_load_lds((gm_t*)(Wp + bsrc[j] + k0),
                    (lds_t*)(Bs + (wave * 4 + j) * 512), 16, 0, 0);
        }
#pragma unroll
        for (int mi = 0; mi < 4; ++mi)
#pragma unroll
            for (int ni = 0; ni < 4; ++ni)
                acc[mi][ni] = __builtin_amdgcn_mfma_f32_16x16x32_f16(
                    af[mi], bfr[ni], acc[mi][ni], 0, 0, 0);
    }
    // After the ki=7 second barrier: no more Bs reads -> qt may reuse Bs.

    // quantize: per (row, this wave's 64 cols) absmax
    // C/D layout: col = lane&15, row = quad*4 + reg  [m89; dtype-independent]
#pragma unroll
    for (int mi = 0; mi < 4; ++mi) {
#pragma unroll
        for (int r = 0; r < 4; ++r) {
            float am = 0.f;
#pragma unroll
            for (int ni = 0; ni < 4; ++ni)
                am = fmaxf(am, fabsf(acc[mi][ni][r]));
            am = fmaxf(am, __shfl_xor(am, 1));   // reduce over l16 (same quad)
            am = fmaxf(am, __shfl_xor(am, 2));
            am = fmaxf(am, __shfl_xor(am, 4));
            am = fmaxf(am, __shfl_xor(am, 8));
            const float sinv = am > 0.f ? 127.f / am : 0.f;
            const int rl = mi * 16 + quad * 4 + r;
#pragma unroll
            for (int ni = 0; ni < 4; ++ni)
                qt[rl * 256 + wn + ni * 16 + l16] =
                    (char)(int)__builtin_rintf(acc[mi][ni][r] * sinv);
            if (l16 == 0) {
                const int row = bm + rl;
                if (row < M) sc[row * 4 + wave] = am * (1.f / 16129.f);
            }
        }
    }
    __syncthreads();

    // coalesced i8 store: thread t -> row t>>2, 64 B chunk (t&3)
    {
        const int rl  = t >> 2;
        const int co  = (t & 3) * 64;
        const int row = bm + rl;
        if (row < M) {
            const int4* s4 = reinterpret_cast<const int4*>(qt + rl * 256 + co);
            int4* d4 = reinterpret_cast<int4*>(nfq + (size_t)row * 256 + co);
#pragma unroll
            for (int j = 0; j < 4; ++j) d4[j] = s4[j];
        }
    }
}

// One wave per destination node; lane = feature f (F=64).
// No LDS, no barriers: chunk metadata broadcast by shuffles.
__global__ __launch_bounds__(128) void edge_aggregate(
    const int* __restrict__ rowptr,
    const int* __restrict__ colind,
    const int* __restrict__ gq,         // i8x4 gaussians per edge
    const char* __restrict__ nfq,       // i8 [N][256] permuted [f*4+k]
    const float* __restrict__ sc,       // f32 [N][4] group scales
    const float* __restrict__ bias,
    float* __restrict__ out,            // [N][64]
    int N)
{
    const int lane = threadIdx.x & 63;
    const int node = (blockIdx.x * blockDim.x + threadIdx.x) >> 6;
    if (node >= N) return;

    const int kk = lane >> 4;           // scale group this lane needs
    const int ii = lane & 15;           // edge slot this lane stages

    const int e0 = rowptr[node];
    const int e1 = rowptr[node + 1];

    float a4[4] = {0.f, 0.f, 0.f, 0.f};   // 4 independent chains
    for (int ec = e0; ec < e1; ec += 16) {
        const int cnt = min(16, e1 - ec);
        const bool v = ii < cnt;
        const int idx = v ? (ec + ii) : e0;          // safe index
        const int c  = colind[idx];                  // lane (kk,ii): col of edge ii
        int g4 = gq[idx];
        if (!v) g4 = 0;                              // dead edges contribute 0
        const float s = sc[c * 4 + kk];              // scale(col_ii, group kk)

        // broadcast cols, issue all 16 gathers back-to-back (16-deep MLP)
        int cj[16];
#pragma unroll
        for (int j = 0; j < 16; ++j) cj[j] = __shfl(c, j);
        int qj[16];
#pragma unroll
        for (int j = 0; j < 16; ++j)
            qj[j] = *reinterpret_cast<const int*>(
                nfq + ((size_t)cj[j] << 8) + (lane << 2));
#pragma unroll
        for (int j = 0; j < 16; ++j) {
            const int   gj = __shfl(g4, j);
            const float sj = __shfl(s, (kk << 4) | j);
            a4[j & 3] += sj * (float)dot4_i8(qj[j], gj);
        }
    }
    out[((size_t)node << 6) + lane] =
        (a4[0] + a4[1]) + (a4[2] + a4[3]) + bias[lane];
}

extern "C" void kernel_launch(void* const* d_in, const int* in_sizes, int n_in,
                              void* d_out, int out_size, void* d_ws, size_t ws_size,
                              hipStream_t stream)
{
    const int*   rowptr    = (const int*)d_in[0];
    const int*   colind    = (const int*)d_in[1];
    // d_in[2] colptr, d_in[3] rowind, d_in[4] permute: inert in forward math
    const float* feat      = (const float*)d_in[5];
    const float* pseudo    = (const float*)d_in[6];
    const float* W_fc      = (const float*)d_in[7];
    const float* mu        = (const float*)d_in[8];
    const float* inv_sigma = (const float*)d_in[9];
    const float* bias      = (const float*)d_in[10];
    float* out = (float*)d_out;

    const int N = in_sizes[0] - 1;        // 50000
    const int E = in_sizes[1];            // 800000
    char*  nfq = (char*)d_ws;                          // i8 [N][256] = 12.8 MB
    float* sc  = (float*)(nfq + (size_t)N * 256);      // f32 [N][4]  =  0.8 MB
    int*   gq  = (int*)(sc + (size_t)N * 4);           // i32 [E]     =  3.2 MB
    f16*   Wp  = (f16*)d_out;             // 128 KB overlay; edge rewrites
                                          // all of d_out afterwards

    hipLaunchKernelGGL(prep, dim3(1024), dim3(256), 0, stream,
                       W_fc, pseudo, mu, inv_sigma, Wp, gq, E);

    hipLaunchKernelGGL(gemm_fused, dim3((N + 63) / 64), dim3(256), 0, stream,
                       feat, Wp, nfq, sc, N);

    hipLaunchKernelGGL(edge_aggregate, dim3((N * 64 + 127) / 128), dim3(128), 0,
                       stream, rowptr, colind, gq, nfq, sc, bias, out, N);
}